// Round 2
// baseline (1522.296 us; speedup 1.0000x reference)
//
#include <hip/hip_runtime.h>
#include <math.h>

typedef unsigned short bfu;   // raw bf16 bits

__device__ __forceinline__ float bs2f(bfu s){
  union{ unsigned int u; float f; } v; v.u = ((unsigned int)s) << 16; return v.f;
}
__device__ __forceinline__ bfu f2bs(float f){
  union{ float ff; unsigned int u; } v; v.ff = f;
  unsigned int u = v.u;
  unsigned int r = (u + 0x7fffu + ((u >> 16) & 1u)) >> 16;   // RNE
  return (bfu)r;
}

// flexible 8-element read: bf16 (uint4) or fp32 (2x float4), element index eidx
__device__ __forceinline__ void ld8f(const void* base, size_t eidx, int f32, float* o){
  if(f32){
    const float* p = (const float*)base + eidx;
    float4 a = *reinterpret_cast<const float4*>(p);
    float4 b = *reinterpret_cast<const float4*>(p+4);
    o[0]=a.x;o[1]=a.y;o[2]=a.z;o[3]=a.w;o[4]=b.x;o[5]=b.y;o[6]=b.z;o[7]=b.w;
  } else {
    union{uint4 u; bfu x[8];} U;
    U.u = *reinterpret_cast<const uint4*>((const bfu*)base + eidx);
    #pragma unroll
    for(int j=0;j<8;++j) o[j]=bs2f(U.x[j]);
  }
}

struct LevelTab { int twoff[13]; int ll[13]; int logh[13]; };
struct WPtrs { const void* p[6]; };

// ---------------- dtype sniff: even bf16 slots of fp32 data have random exps -
__global__ __launch_bounds__(256) void k_sniff(const bfu* __restrict__ x, int* __restrict__ flag){
  __shared__ int cnt;
  if(threadIdx.x==0) cnt = 0;
  __syncthreads();
  int c = 0;
  for(int j=threadIdx.x; j<4096; j+=256){
    bfu v = x[2*j];
    int e = (v>>7)&0xFF;
    if(e >= 0xC0) c++;
  }
  atomicAdd(&cnt, c);
  __syncthreads();
  if(threadIdx.x==0) flag[0] = (cnt > 64) ? 1 : 0;
}

// ---------------- small-array canonicalization to bf16 -----------------------
// CSM layout: 0=ec_s,128=ec_d,256=rc_e,384=rc_o,512=ln_w,640=ln_b
__global__ __launch_bounds__(256) void k_cvt_small(
    const void* lnw, const void* lnb, const void* ecs, const void* ecd,
    const void* rce, const void* rco, bfu* __restrict__ CSM, const int* __restrict__ FLAG){
  int f32 = FLAG[0];
  const void* src[6] = {ecs, ecd, rce, rco, lnw, lnb};
  int tid = threadIdx.x;
  for(int a=0; a<6; ++a)
    for(int j=tid; j<128; j+=256)
      CSM[a*128+j] = f32 ? f2bs(((const float*)src[a])[j]) : ((const bfu*)src[a])[j];
}

// ---------------- weight transpose: W[i][o][f] (f<64) -> T[f][i][o], bf16 ----
__global__ __launch_bounds__(64) void k_wtrans(WPtrs wp, bfu* __restrict__ T, const int* __restrict__ FLAG){
  int f32 = FLAG[0];
  int o = blockIdx.x*64 + threadIdx.x;   // 0..127
  int i = blockIdx.y;                    // 0..127
  int w = blockIdx.z;                    // 0..5
  size_t sb = ((size_t)i*128 + o)*64;
  bfu* dst = T + (size_t)w*64*128*128;
  #pragma unroll 4
  for(int f=0; f<64; ++f){
    bfu v = f32 ? f2bs(((const float*)wp.p[w])[sb+f]) : ((const bfu*)wp.p[w])[sb+f];
    dst[((size_t)f*128 + i)*128 + o] = v;
  }
}

// ---------------- twiddle tables per level: cos at [f*h+t], sin after l*h ----
__global__ __launch_bounds__(256) void k_twgen(LevelTab lt, float* __restrict__ tw){
  int lev = blockIdx.y;
  int logh = lt.logh[lev];
  int h = 1 << logh;
  int l = lt.ll[lev];
  int tot = l*h;
  int idx = blockIdx.x*256 + threadIdx.x;
  if(idx >= tot) return;
  int t = idx & (h-1);
  int f = idx >> logh;
  int m = (f*t) & (h-1);
  float th = 6.283185307179586f * ((float)m / (float)h);
  float s, c;
  sincosf(th, &s, &c);
  tw[lt.twoff[lev] + idx] = c;
  tw[lt.twoff[lev] + tot + idx] = s;
}

// ---------------- decompose: x (B,2h,128) -> d,s (B,h,128) ------------------
__global__ __launch_bounds__(256) void k_decomp(
    const void* __restrict__ xin, int use_flag, bfu* __restrict__ dout, bfu* __restrict__ sout,
    const bfu* __restrict__ CSM, int half, int loghalf, const int* __restrict__ FLAG)
{
  int f32 = use_flag ? FLAG[0] : 0;
  __shared__ float Fs[16][8], Fd[16][8];
  int tid = threadIdx.x;
  if(tid < 128){ Fs[tid>>3][tid&7] = bs2f(CSM[tid]); Fd[tid>>3][tid&7] = bs2f(CSM[128+tid]); }
  __syncthreads();
  int idx = blockIdx.x*256 + tid;
  if(idx >= 16*half*16) return;
  int c  = idx & 15;
  int bt = idx >> 4;                 // b*half + t
  int t  = bt & (half-1);
  int b  = bt >> loghalf;
  size_t pbase = (((size_t)(b*(half<<1) + (t<<1))) << 7) + (c<<3);
  float xa[16];
  ld8f(xin, pbase,       f32, xa);
  ld8f(xin, pbase + 128, f32, xa+8);
  float d8[8] = {0,0,0,0,0,0,0,0}, s8[8] = {0,0,0,0,0,0,0,0};
  #pragma unroll
  for(int j=0;j<16;++j){
    float v = xa[j];
    #pragma unroll
    for(int k=0;k<8;++k){ d8[k] += v*Fd[j][k]; s8[k] += v*Fs[j][k]; }
  }
  union{ uint4 u; bfu x[8]; } Od, Os;
  #pragma unroll
  for(int k=0;k<8;++k){ Od.x[k] = f2bs(d8[k]); Os.x[k] = f2bs(s8[k]); }
  size_t ob = (((size_t)bt) << 7) + (c<<3);
  *reinterpret_cast<uint4*>(dout + ob) = Od.u;
  *reinterpret_cast<uint4*>(sout + ob) = Os.u;
}

// ---------------- forward truncated DFT (unnormalized), K-split -------------
// grid: (ceil(l/32), B, 2*np)   block 128
// dst layout: [part][re/im][B][64][128] fp32 partial sums
#define TC 64
__global__ __launch_bounds__(128) void k_fwdft(
    const bfu* __restrict__ dsrc, const bfu* __restrict__ ssrc,
    float* __restrict__ ftd, float* __restrict__ fts,
    const float* __restrict__ cosT, const float* __restrict__ sinT,
    int h, int l, int np, int tlen)
{
  int z = blockIdx.z;
  int tr = z / np;
  int part = z - tr*np;
  const bfu* src = tr ? ssrc : dsrc;
  float* dst = tr ? fts : ftd;
  int b = blockIdx.y;
  int f0 = blockIdx.x * 32;
  int tid = threadIdx.x;
  int chq = tid & 31;      // channel quad: ch = chq*4..chq*4+3
  int fq  = tid >> 5;      // freq octet: f = f0 + fq*8 + ff

  __shared__ float ls[TC][128];
  __shared__ float ltw[TC][64];   // [t][ cos f'(0..31) | sin f'(32..63) ]
  float accr[8][4] = {};
  float acci[8][4] = {};

  int t0base = part * tlen;
  for(int t0 = t0base; t0 < t0base + tlen; t0 += TC){
    int rem = t0base + tlen - t0;
    int tc = rem < TC ? rem : TC;
    #pragma unroll
    for(int rr=0; rr<8; ++rr){
      int e = rr*128 + tid;          // 0..1023 uint4 slots
      int r = e >> 4, ci = (e & 15) << 3;
      if(r < tc){
        union{ uint4 u; bfu x[8]; } U;
        U.u = *reinterpret_cast<const uint4*>(src + (((size_t)(b*h + t0 + r)) << 7) + ci);
        #pragma unroll
        for(int j=0;j<8;++j) ls[r][ci+j] = bs2f(U.x[j]);
      }
    }
    #pragma unroll
    for(int ee=0; ee<16; ++ee){
      int e = ee*128 + tid;          // 0..2047
      int t = e >> 5, ff = e & 31;
      int f = f0 + ff;
      float c = 0.f, s = 0.f;
      if(f < l && t < tc){
        c = cosT[(size_t)f*h + t0 + t];
        s = sinT[(size_t)f*h + t0 + t];
      }
      ltw[t][ff] = c; ltw[t][32+ff] = s;
    }
    __syncthreads();
    for(int t=0; t<tc; ++t){
      float4 v  = *reinterpret_cast<const float4*>(&ls[t][chq<<2]);
      float4 c0 = *reinterpret_cast<const float4*>(&ltw[t][fq*8]);
      float4 c1 = *reinterpret_cast<const float4*>(&ltw[t][fq*8+4]);
      float4 s0 = *reinterpret_cast<const float4*>(&ltw[t][32+fq*8]);
      float4 s1 = *reinterpret_cast<const float4*>(&ltw[t][32+fq*8+4]);
      float vv[4] = {v.x, v.y, v.z, v.w};
      float cc[8] = {c0.x,c0.y,c0.z,c0.w,c1.x,c1.y,c1.z,c1.w};
      float ss[8] = {s0.x,s0.y,s0.z,s0.w,s1.x,s1.y,s1.z,s1.w};
      #pragma unroll
      for(int ff=0; ff<8; ++ff){
        #pragma unroll
        for(int j=0;j<4;++j){
          accr[ff][j] += vv[j]*cc[ff];
          acci[ff][j] -= vv[j]*ss[ff];
        }
      }
    }
    __syncthreads();
  }
  #pragma unroll
  for(int ff=0; ff<8; ++ff){
    int f = f0 + fq*8 + ff;
    if(f < l){
      size_t br = ((((size_t)part*2 + 0)*16 + b)*64 + f)*128 + (chq<<2);
      size_t bi = ((((size_t)part*2 + 1)*16 + b)*64 + f)*128 + (chq<<2);
      *reinterpret_cast<float4*>(&dst[br]) = make_float4(accr[ff][0],accr[ff][1],accr[ff][2],accr[ff][3]);
      *reinterpret_cast<float4*>(&dst[bi]) = make_float4(acci[ff][0],acci[ff][1],acci[ff][2],acci[ff][3]);
    }
  }
}

// ---------------- mode mixing + irfft prescale ------------------------------
__global__ __launch_bounds__(128) void k_modemix(
    const float* __restrict__ ftd, const float* __restrict__ fts,
    const bfu* __restrict__ WT,
    float* __restrict__ Yd, float* __restrict__ Yu,
    int h, int l, int np)
{
  int f = blockIdx.x, b = blockIdx.y, o = threadIdx.x;
  __shared__ float sdr[128], sdi[128], ssr[128], ssi[128];
  {
    float ar=0, ai=0, br=0, bi=0;
    for(int p=0;p<np;++p){
      size_t base  = ((((size_t)p*2+0)*16 + b)*64 + f)*128 + o;
      size_t basei = ((((size_t)p*2+1)*16 + b)*64 + f)*128 + o;
      ar += ftd[base]; ai += ftd[basei];
      br += fts[base]; bi += fts[basei];
    }
    sdr[o]=ar; sdi[o]=ai; ssr[o]=br; ssi[o]=bi;
  }
  __syncthreads();
  const size_t WSZ = (size_t)64*128*128;
  float ydr=0, ydi=0, yur=0, yui=0;
  for(int i=0;i<128;++i){
    float dr=sdr[i], di=sdi[i], sr=ssr[i], si=ssi[i];
    size_t wb = (((size_t)f*128)+i)*128 + o;
    float Ar = bs2f(WT[wb]);
    float Ai = bs2f(WT[WSZ + wb]);
    float Br = bs2f(WT[2*WSZ + wb]);
    float Bi = bs2f(WT[3*WSZ + wb]);
    float Cr = bs2f(WT[4*WSZ + wb]);
    float Ci = bs2f(WT[5*WSZ + wb]);
    ydr += dr*Ar - di*Ai + sr*Br - si*Bi;
    ydi += dr*Ai + di*Ar + sr*Bi + si*Br;
    yur += dr*Cr - di*Ci;
    yui += dr*Ci + di*Cr;
  }
  float sc = 2.0f / (float)h;
  bool edge = (f==0) || (2*f == h);
  if(edge) sc = 1.0f / (float)h;
  const size_t YIM = (size_t)16*64*128;
  size_t ob = (((size_t)(b*64+f)) << 7) + o;
  Yd[ob] = ydr*sc; Yd[YIM+ob] = edge ? 0.f : ydi*sc;
  Yu[ob] = yur*sc; Yu[YIM+ob] = edge ? 0.f : yui*sc;
}

// ---------------- inverse truncated DFT -------------------------------------
__global__ __launch_bounds__(128) void k_invdft(
    const float* __restrict__ Yd, const float* __restrict__ Yu,
    bfu* __restrict__ ud, bfu* __restrict__ us,
    const float* __restrict__ cosT, const float* __restrict__ sinT,
    int h, int l)
{
  const float* Y = blockIdx.z ? Yu : Yd;
  bfu* outp = blockIdx.z ? us : ud;
  int b = blockIdx.y;
  int t0 = blockIdx.x * 64;
  int tid = threadIdx.x;
  int chq = tid & 31, sub = tid >> 5;

  __shared__ float lyr[16][128], lyi[16][128];
  __shared__ float ltc[16][64], lts[16][64];
  float acc[16][4] = {};
  const size_t YIM = (size_t)16*64*128;

  for(int fc=0; fc<l; fc+=16){
    #pragma unroll
    for(int ee=0; ee<16; ++ee){
      int e = ee*128 + tid;
      int f = e >> 7, ch = e & 127;
      int fg = fc + f;
      float yr=0.f, yi=0.f;
      if(fg < l){
        yr = Y[(((size_t)(b*64+fg))<<7) + ch];
        yi = Y[YIM + (((size_t)(b*64+fg))<<7) + ch];
      }
      lyr[f][ch]=yr; lyi[f][ch]=yi;
    }
    #pragma unroll
    for(int ee=0; ee<8; ++ee){
      int e = ee*128 + tid;
      int f = e >> 6, tt = e & 63;
      int fg = fc + f, tg = t0 + tt;
      float c=0.f, s=0.f;
      if(fg < l && tg < h){
        c = cosT[(size_t)fg*h + tg];
        s = sinT[(size_t)fg*h + tg];
      }
      ltc[f][tt]=c; lts[f][tt]=s;
    }
    __syncthreads();
    for(int f=0; f<16; ++f){
      float4 yr4 = *reinterpret_cast<const float4*>(&lyr[f][chq<<2]);
      float4 yi4 = *reinterpret_cast<const float4*>(&lyi[f][chq<<2]);
      float4 c0 = *reinterpret_cast<const float4*>(&ltc[f][sub*16]);
      float4 c1 = *reinterpret_cast<const float4*>(&ltc[f][sub*16+4]);
      float4 c2 = *reinterpret_cast<const float4*>(&ltc[f][sub*16+8]);
      float4 c3 = *reinterpret_cast<const float4*>(&ltc[f][sub*16+12]);
      float4 s0 = *reinterpret_cast<const float4*>(&lts[f][sub*16]);
      float4 s1 = *reinterpret_cast<const float4*>(&lts[f][sub*16+4]);
      float4 s2 = *reinterpret_cast<const float4*>(&lts[f][sub*16+8]);
      float4 s3 = *reinterpret_cast<const float4*>(&lts[f][sub*16+12]);
      float yrr[4] = {yr4.x,yr4.y,yr4.z,yr4.w};
      float yii[4] = {yi4.x,yi4.y,yi4.z,yi4.w};
      float cc[16] = {c0.x,c0.y,c0.z,c0.w,c1.x,c1.y,c1.z,c1.w,
                      c2.x,c2.y,c2.z,c2.w,c3.x,c3.y,c3.z,c3.w};
      float ssv[16]= {s0.x,s0.y,s0.z,s0.w,s1.x,s1.y,s1.z,s1.w,
                      s2.x,s2.y,s2.z,s2.w,s3.x,s3.y,s3.z,s3.w};
      #pragma unroll
      for(int tt=0;tt<16;++tt){
        #pragma unroll
        for(int j=0;j<4;++j)
          acc[tt][j] += yrr[j]*cc[tt] - yii[j]*ssv[tt];
      }
    }
    __syncthreads();
  }
  #pragma unroll
  for(int tt=0; tt<16; ++tt){
    int t = t0 + sub*16 + tt;
    if(t < h){
      union{ uint2 u; bfu x[4]; } O;
      #pragma unroll
      for(int j=0;j<4;++j) O.x[j] = f2bs(acc[tt][j]);
      *reinterpret_cast<uint2*>(outp + (((size_t)(b*h + t))<<7) + (chq<<2)) = O.u;
    }
  }
}

// ---------------- LayerNorm + exact GELU on (16,1,128) ----------------------
__global__ __launch_bounds__(128) void k_lngelu(
    const bfu* __restrict__ xin, const bfu* __restrict__ CSM, bfu* __restrict__ xout)
{
  int b = blockIdx.x, tid = threadIdx.x;
  float v = bs2f(xin[b*128 + tid]);
  float s1 = v, s2 = v*v;
  #pragma unroll
  for(int o=32; o; o>>=1){ s1 += __shfl_down(s1,o); s2 += __shfl_down(s2,o); }
  __shared__ float red[2][2];
  int w = tid >> 6;
  if((tid & 63) == 0){ red[w][0]=s1; red[w][1]=s2; }
  __syncthreads();
  float m  = (red[0][0]+red[1][0]) * (1.0f/128.0f);
  float ms = (red[0][1]+red[1][1]) * (1.0f/128.0f);
  float var = ms - m*m;
  float xn = (v - m) * rsqrtf(var + 1e-5f) * bs2f(CSM[512+tid]) + bs2f(CSM[640+tid]);
  float g = 0.5f * xn * (1.0f + erff(xn * 0.70710678118654752f));
  xout[b*128 + tid] = f2bs(g);
}

// ---------------- reconstruction step ---------------------------------------
__global__ __launch_bounds__(256) void k_recon(
    const bfu* __restrict__ xin, const bfu* __restrict__ usp, const bfu* __restrict__ udp,
    const bfu* __restrict__ CSM, void* __restrict__ xout, int h, int logh,
    int is_final, const int* __restrict__ FLAG)
{
  int f32 = is_final ? FLAG[0] : 0;
  __shared__ float Fe[16][8], Fo[16][8];
  int tid = threadIdx.x;
  if(tid < 128){ Fe[tid>>3][tid&7] = bs2f(CSM[256+tid]); Fo[tid>>3][tid&7] = bs2f(CSM[384+tid]); }
  __syncthreads();
  int idx = blockIdx.x*256 + tid;
  if(idx >= 16*h*16) return;
  int c  = idx & 15;
  int bt = idx >> 4;
  int t  = bt & (h-1);
  int b  = bt >> logh;
  size_t base = (((size_t)bt) << 7) + (c<<3);
  union{ uint4 u; bfu x[8]; } X, U, D;
  X.u = *reinterpret_cast<const uint4*>(xin + base);
  U.u = *reinterpret_cast<const uint4*>(usp + base);
  D.u = *reinterpret_cast<const uint4*>(udp + base);
  float y[16];
  #pragma unroll
  for(int j=0;j<8;++j){ y[j] = bs2f(X.x[j]) + bs2f(U.x[j]); y[8+j] = bs2f(D.x[j]); }
  float e8[8] = {0,0,0,0,0,0,0,0}, o8[8] = {0,0,0,0,0,0,0,0};
  #pragma unroll
  for(int j=0;j<16;++j){
    float v = y[j];
    #pragma unroll
    for(int k=0;k<8;++k){ e8[k] += v*Fe[j][k]; o8[k] += v*Fo[j][k]; }
  }
  size_t ob = (((size_t)(b*(h<<1) + (t<<1))) << 7) + (c<<3);
  if(f32){
    float* po = (float*)xout;
    *reinterpret_cast<float4*>(po + ob)       = make_float4(e8[0],e8[1],e8[2],e8[3]);
    *reinterpret_cast<float4*>(po + ob + 4)   = make_float4(e8[4],e8[5],e8[6],e8[7]);
    *reinterpret_cast<float4*>(po + ob + 128) = make_float4(o8[0],o8[1],o8[2],o8[3]);
    *reinterpret_cast<float4*>(po + ob + 132) = make_float4(o8[4],o8[5],o8[6],o8[7]);
  } else {
    union{ uint4 u; bfu x[8]; } Oe, Oo;
    #pragma unroll
    for(int k=0;k<8;++k){ Oe.x[k] = f2bs(e8[k]); Oo.x[k] = f2bs(o8[k]); }
    bfu* po = (bfu*)xout;
    *reinterpret_cast<uint4*>(po + ob)       = Oe.u;
    *reinterpret_cast<uint4*>(po + ob + 128) = Oo.u;
  }
}

// ============================================================================
extern "C" void kernel_launch(void* const* d_in, const int* in_sizes, int n_in,
                              void* d_out, int out_size, void* d_ws, size_t ws_size,
                              hipStream_t stream)
{
  (void)in_sizes; (void)n_in; (void)out_size; (void)ws_size;
  const void* x0 = d_in[0];
  WPtrs wp;
  for(int w=0;w<6;++w) wp.p[w] = d_in[1+w];

  char* ws = (char*)d_ws;
  size_t off = 0;
  auto carve = [&](size_t bytes)->char*{
    char* p = ws + off; off += (bytes + 255) & ~(size_t)255; return p; };

  int* FLAG = (int*)carve(256);
  bfu* CSM  = (bfu*)carve(768*2);
  bfu* SA   = (bfu*)carve((size_t)16*4096*128*2);   // even-level s outputs
  bfu* SB   = (bfu*)carve((size_t)16*2048*128*2);   // odd-level s outputs
  bfu *Ud[13], *Us[13];
  for(int i=0;i<13;++i) Ud[i] = (bfu*)carve((size_t)16*(4096>>i)*128*2);
  for(int i=0;i<13;++i) Us[i] = (bfu*)carve((size_t)16*(4096>>i)*128*2);
  char* R = carve((size_t)35651584);
  bfu*   Dscr = (bfu*)R;                                  // 16 MiB
  float* FTD  = (float*)(R + 16777216);                   //  8 MiB
  float* FTS  = (float*)(R + 16777216 + 8388608);         //  8 MiB
  float* Yd   = (float*)(R + 16777216 + 2*8388608);       //  1 MiB
  float* Yu   = (float*)(R + 16777216 + 2*8388608 + 1048576);
  bfu*   XA   = (bfu*)R;
  bfu*   XB   = (bfu*)(R + 16777216);
  bfu*   WT   = (bfu*)carve((size_t)6*64*128*128*2);

  LevelTab lt;
  int hv[13], lv2[13], npv[13];
  int acc = 0;
  for(int i=0;i<13;++i){
    int h = 4096 >> i;
    int l = (h==1) ? 1 : ((h/2+1) < 64 ? (h/2+1) : 64);
    hv[i]=h; lv2[i]=l;
    lt.twoff[i]=acc; lt.ll[i]=l; lt.logh[i]=12-i;
    acc += 2*l*h;
    int np = h/64; if(np>8) np=8; if(np<1) np=1;
    npv[i]=np;
  }
  float* TW = (float*)carve((size_t)acc*4);

  k_sniff<<<dim3(1),256,0,stream>>>((const bfu*)x0, FLAG);
  k_cvt_small<<<dim3(1),256,0,stream>>>(d_in[7], d_in[8], d_in[9], d_in[10], d_in[11], d_in[12], CSM, FLAG);
  k_wtrans<<<dim3(2,128,6),64,0,stream>>>(wp, WT, FLAG);
  k_twgen<<<dim3(1024,13),256,0,stream>>>(lt, TW);

  const void* cur = x0;
  for(int i=0;i<13;++i){
    int h=hv[i], l=lv2[i], np=npv[i], logh=12-i;
    const float* cT = TW + lt.twoff[i];
    const float* sT = cT + (size_t)l*h;
    bfu* sout = (i & 1) ? SB : SA;
    int tot = 16*h*16;
    k_decomp<<<dim3((tot+255)/256),256,0,stream>>>(cur, (i==0)?1:0, Dscr, sout, CSM, h, logh, FLAG);
    k_fwdft<<<dim3((l+31)/32,16,2*np),128,0,stream>>>(Dscr, sout, FTD, FTS, cT, sT, h, l, np, h/np);
    k_modemix<<<dim3(l,16),128,0,stream>>>(FTD, FTS, WT, Yd, Yu, h, l, np);
    k_invdft<<<dim3((h+63)/64,16,2),128,0,stream>>>(Yd, Yu, Ud[i], Us[i], cT, sT, h, l);
    cur = sout;
  }
  k_lngelu<<<dim3(16),128,0,stream>>>(SA, CSM, XA);   // level 12 (even) wrote SA
  bfu* rin = XA;
  for(int i=12;i>=0;--i){
    int h = hv[i];
    void* rout = (i==0) ? d_out : (void*)((rin==XA) ? XB : XA);
    int tot = 16*h*16;
    k_recon<<<dim3((tot+255)/256),256,0,stream>>>(rin, Us[i], Ud[i], CSM, rout, h, 12-i, (i==0)?1:0, FLAG);
    rin = (bfu*)rout;
  }
}

// Round 3
// 1471.297 us; speedup vs baseline: 1.0347x; 1.0347x over previous
//
#include <hip/hip_runtime.h>
#include <math.h>

typedef unsigned short bfu;   // raw bf16 bits
typedef short bf16x8 __attribute__((ext_vector_type(8)));
typedef float f32x4 __attribute__((ext_vector_type(4)));

__device__ __forceinline__ float bs2f(bfu s){
  union{ unsigned int u; float f; } v; v.u = ((unsigned int)s) << 16; return v.f;
}
__device__ __forceinline__ bfu f2bs(float f){
  union{ float ff; unsigned int u; } v; v.ff = f;
  unsigned int u = v.u;
  unsigned int r = (u + 0x7fffu + ((u >> 16) & 1u)) >> 16;   // RNE
  return (bfu)r;
}

struct LevelTab { int twoff[13]; int ll[13]; int logh[13]; };
struct WPtrs { const void* p[6]; };

// ---------------- dtype sniff ------------------------------------------------
__global__ __launch_bounds__(256) void k_sniff(const bfu* __restrict__ x, int* __restrict__ flag){
  __shared__ int cnt;
  if(threadIdx.x==0) cnt = 0;
  __syncthreads();
  int c = 0;
  for(int j=threadIdx.x; j<4096; j+=256){
    bfu v = x[2*j];
    int e = (v>>7)&0xFF;
    if(e >= 0xC0) c++;
  }
  atomicAdd(&cnt, c);
  __syncthreads();
  if(threadIdx.x==0) flag[0] = (cnt > 64) ? 1 : 0;
}

// ---------------- small arrays -> bf16. 0=ec_s,128=ec_d,256=rc_e,384=rc_o,512=ln_w,640=ln_b
__global__ __launch_bounds__(256) void k_cvt_small(
    const void* lnw, const void* lnb, const void* ecs, const void* ecd,
    const void* rce, const void* rco, bfu* __restrict__ CSM, const int* __restrict__ FLAG){
  int f32 = FLAG[0];
  const void* src[6] = {ecs, ecd, rce, rco, lnw, lnb};
  int tid = threadIdx.x;
  for(int a=0; a<6; ++a)
    for(int j=tid; j<128; j+=256)
      CSM[a*128+j] = f32 ? f2bs(((const float*)src[a])[j]) : ((const bfu*)src[a])[j];
}

// ---------------- weight transpose: W[i][o][f] -> T[f][i][o], bf16 -----------
__global__ __launch_bounds__(64) void k_wtrans(WPtrs wp, bfu* __restrict__ T, const int* __restrict__ FLAG){
  int f32 = FLAG[0];
  int o = blockIdx.x*64 + threadIdx.x;
  int i = blockIdx.y;
  int w = blockIdx.z;
  size_t sb = ((size_t)i*128 + o)*64;
  bfu* dst = T + (size_t)w*64*128*128;
  #pragma unroll 4
  for(int f=0; f<64; ++f){
    bfu v = f32 ? f2bs(((const float*)wp.p[w])[sb+f]) : ((const bfu*)wp.p[w])[sb+f];
    dst[((size_t)f*128 + i)*128 + o] = v;
  }
}

// ---------------- bf16 twiddle matrices for MFMA levels 0..5 -----------------
// TWF[level]: [r(128)][t(h)] ; r<64: cos(2*pi*r*t/h), r>=64: -sin(2*pi*(r-64)*t/h)
// TWI[level]: [t(h)][f2(128)]; f2<64: cos, f2>=64: -sin
__global__ __launch_bounds__(256) void k_twgenF(bfu* __restrict__ TWF, bfu* __restrict__ TWI){
  int e = blockIdx.x*256 + threadIdx.x;      // 0..1032191
  int kind = blockIdx.y;
  const int offs[7] = {0,524288,786432,917504,983040,1015808,1032192};
  int le = 5;
  #pragma unroll
  for(int i=0;i<6;++i){ if(e < offs[i+1]){ le = i; break; } }
  int rem = e - offs[le];
  int logh = 12 - le;
  int h = 1 << logh;
  int f, t, neg;
  if(kind==0){ int r = rem >> logh; t = rem & (h-1); f = (r<64)?r:(r-64); neg = (r>=64); }
  else       { t = rem >> 7; int f2 = rem & 127;     f = (f2<64)?f2:(f2-64); neg = (f2>=64); }
  int m = (f*t) & (h-1);
  float th = 6.283185307179586f * ((float)m / (float)h);
  float s, c; sincosf(th, &s, &c);
  float val = neg ? -s : c;
  if(kind==0) TWF[e] = f2bs(val); else TWI[e] = f2bs(val);
}

// ---------------- fp32 twiddles for deep levels (cos at [f*h+t], sin after l*h)
__global__ __launch_bounds__(256) void k_twgen(LevelTab lt, float* __restrict__ tw){
  int lev = blockIdx.y;
  int logh = lt.logh[lev];
  int h = 1 << logh;
  int l = lt.ll[lev];
  int tot = l*h;
  int idx = blockIdx.x*256 + threadIdx.x;
  if(idx >= tot) return;
  int t = idx & (h-1);
  int f = idx >> logh;
  int m = (f*t) & (h-1);
  float th = 6.283185307179586f * ((float)m / (float)h);
  float s, c; sincosf(th, &s, &c);
  tw[lt.twoff[lev] + idx] = c;
  tw[lt.twoff[lev] + tot + idx] = s;
}

// ---------------- level-0 decompose: x (B,2h,128) row-major -> dT,sT [b][ch][h]
__global__ __launch_bounds__(256) void k_decomp0(
    const void* __restrict__ xin, bfu* __restrict__ dT, bfu* __restrict__ sT,
    const bfu* __restrict__ CSM, int h, const int* __restrict__ FLAG)
{
  int f32 = FLAG[0];
  __shared__ float ls[64][132];
  __shared__ float Fd[16][8], Fs[16][8];
  int tid = threadIdx.x;
  if(tid < 128){ Fs[tid>>3][tid&7] = bs2f(CSM[tid]); Fd[tid>>3][tid&7] = bs2f(CSM[128+tid]); }
  int b = blockIdx.y;
  int t0in = blockIdx.x * 64;
  if(f32){
    const float* src = (const float*)xin + ((size_t)b*2*h + t0in)*128;
    #pragma unroll
    for(int it=0; it<8; ++it){
      int e = it*256 + tid;
      int row = e>>5, cq = e&31;
      float4 v = *reinterpret_cast<const float4*>(src + (size_t)row*128 + cq*4);
      ls[row][cq*4+0]=v.x; ls[row][cq*4+1]=v.y; ls[row][cq*4+2]=v.z; ls[row][cq*4+3]=v.w;
    }
  } else {
    const bfu* src = (const bfu*)xin + ((size_t)b*2*h + t0in)*128;
    #pragma unroll
    for(int it=0; it<4; ++it){
      int e = it*256 + tid;
      int row = e>>4, cq = e&15;
      union{uint4 u; bfu x[8];} U;
      U.u = *reinterpret_cast<const uint4*>(src + (size_t)row*128 + cq*8);
      #pragma unroll
      for(int j=0;j<8;++j) ls[row][cq*8+j] = bs2f(U.x[j]);
    }
  }
  __syncthreads();
  int g = tid>>7, ch = tid&127;
  int c = ch>>3, kp = ch&7;
  float fdE[8], fdO[8], fsE[8], fsO[8];
  #pragma unroll
  for(int j=0;j<8;++j){ fdE[j]=Fd[j][kp]; fdO[j]=Fd[8+j][kp]; fsE[j]=Fs[j][kp]; fsO[j]=Fs[8+j][kp]; }
  union{ uint4 u[2]; bfu x[16]; } OD, OS;
  #pragma unroll
  for(int tl=0; tl<16; ++tl){
    int rl = 2*(g*16+tl);
    const float* ev = &ls[rl][c*8];
    const float* od = &ls[rl+1][c*8];
    float d=0.f, s=0.f;
    #pragma unroll
    for(int j=0;j<8;++j){
      d += ev[j]*fdE[j] + od[j]*fdO[j];
      s += ev[j]*fsE[j] + od[j]*fsO[j];
    }
    OD.x[tl] = f2bs(d); OS.x[tl] = f2bs(s);
  }
  size_t obase = ((size_t)b*128 + ch)*h + (size_t)(t0in>>1) + g*16;
  *reinterpret_cast<uint4*>(dT + obase)     = OD.u[0];
  *reinterpret_cast<uint4*>(dT + obase + 8) = OD.u[1];
  *reinterpret_cast<uint4*>(sT + obase)     = OS.u[0];
  *reinterpret_cast<uint4*>(sT + obase + 8) = OS.u[1];
}

// ---------------- transposed decompose (levels >=1): inT [b][ch][2h] -> dT,sT [b][ch][h]
__global__ __launch_bounds__(256) void k_decompT(
    const bfu* __restrict__ inT, bfu* __restrict__ dT, bfu* __restrict__ sT,
    const bfu* __restrict__ CSM, int h, int total)
{
  __shared__ float Fd[16][8], Fs[16][8];
  int tid = threadIdx.x;
  if(tid < 128){ Fs[tid>>3][tid&7] = bs2f(CSM[tid]); Fd[tid>>3][tid&7] = bs2f(CSM[128+tid]); }
  __syncthreads();
  int idx = blockIdx.x*256 + tid;
  if(idx >= total) return;
  if(h >= 4){
    int nto = h>>2;
    int to = idx & (nto-1);
    int bc = idx / nto;
    int c = bc & 15, b = bc >> 4;
    const bfu* base = inT + ((size_t)b*128 + c*8)*(size_t)(2*h) + to*8;
    float d8[4][8] = {}, s8[4][8] = {};
    #pragma unroll
    for(int k=0;k<8;++k){
      union{uint4 u; bfu x[8];} U;
      U.u = *reinterpret_cast<const uint4*>(base + (size_t)k*(2*h));
      const float* fdE = Fd[k]; const float* fdO = Fd[8+k];
      const float* fsE = Fs[k]; const float* fsO = Fs[8+k];
      #pragma unroll
      for(int tl=0; tl<4; ++tl){
        float ev = bs2f(U.x[2*tl]), od = bs2f(U.x[2*tl+1]);
        #pragma unroll
        for(int kp=0;kp<8;++kp){
          d8[tl][kp] += ev*fdE[kp] + od*fdO[kp];
          s8[tl][kp] += ev*fsE[kp] + od*fsO[kp];
        }
      }
    }
    #pragma unroll
    for(int kp=0;kp<8;++kp){
      union{uint2 u; bfu x[4];} Od, Os;
      #pragma unroll
      for(int tl=0;tl<4;++tl){ Od.x[tl]=f2bs(d8[tl][kp]); Os.x[tl]=f2bs(s8[tl][kp]); }
      size_t ob = ((size_t)b*128 + c*8 + kp)*h + to*4;
      *reinterpret_cast<uint2*>(dT + ob) = Od.u;
      *reinterpret_cast<uint2*>(sT + ob) = Os.u;
    }
  } else {
    int c = idx & 15, b = idx >> 4;
    const bfu* base = inT + ((size_t)b*128 + c*8)*(size_t)(2*h);
    for(int tl=0; tl<h; ++tl){
      float d8[8]={}, s8[8]={};
      for(int k=0;k<8;++k){
        float ev = bs2f(base[(size_t)k*2*h + 2*tl]);
        float od = bs2f(base[(size_t)k*2*h + 2*tl+1]);
        #pragma unroll
        for(int kp=0;kp<8;++kp){
          d8[kp] += ev*Fd[k][kp] + od*Fd[8+k][kp];
          s8[kp] += ev*Fs[k][kp] + od*Fs[8+k][kp];
        }
      }
      for(int kp=0;kp<8;++kp){
        size_t ob = ((size_t)b*128 + c*8 + kp)*h + tl;
        dT[ob] = f2bs(d8[kp]); sT[ob] = f2bs(s8[kp]);
      }
    }
  }
}

// ---------------- MFMA forward DFT: FTP[p][sig][b][row(128)][ch(128)] fp32 ---
__global__ __launch_bounds__(256) void k_fwdft_mfma(
    const bfu* __restrict__ dT, const bfu* __restrict__ sT,
    const bfu* __restrict__ TWFl, float* __restrict__ FTP,
    int h, int Kpart)
{
  int p = blockIdx.x, b = blockIdx.y, sig = blockIdx.z;
  const bfu* SIG = (sig ? sT : dT) + (size_t)b*128*h;
  __shared__ bfu lsA[128*72];
  __shared__ bfu lsB[128*72];
  int tid = threadIdx.x;
  int wave = tid>>6, lane = tid&63;
  int mh = (wave>>1)*64, nh = (wave&1)*64;
  int ml = lane&15, q = lane>>4;
  f32x4 acc[4][4];
  #pragma unroll
  for(int i=0;i<4;++i){
    #pragma unroll
    for(int j=0;j<4;++j) acc[i][j] = (f32x4)0.f;
  }
  int k0base = p*Kpart;
  for(int kc=0; kc<Kpart; kc+=64){
    int k0 = k0base + kc;
    #pragma unroll
    for(int it=0; it<4; ++it){
      int slot = it*256 + tid;
      int row = slot>>3, kq = slot&7;
      *reinterpret_cast<uint4*>(&lsA[row*72 + kq*8]) =
        *reinterpret_cast<const uint4*>(&TWFl[(size_t)row*h + k0 + kq*8]);
      *reinterpret_cast<uint4*>(&lsB[row*72 + kq*8]) =
        *reinterpret_cast<const uint4*>(&SIG[(size_t)row*h + k0 + kq*8]);
    }
    __syncthreads();
    #pragma unroll
    for(int kk=0; kk<64; kk+=32){
      bf16x8 af[4], bfr[4];
      #pragma unroll
      for(int mi=0;mi<4;++mi)
        af[mi] = *reinterpret_cast<const bf16x8*>(&lsA[(mh+mi*16+ml)*72 + kk + q*8]);
      #pragma unroll
      for(int ni=0;ni<4;++ni)
        bfr[ni] = *reinterpret_cast<const bf16x8*>(&lsB[(nh+ni*16+ml)*72 + kk + q*8]);
      #pragma unroll
      for(int mi=0;mi<4;++mi){
        #pragma unroll
        for(int ni=0;ni<4;++ni)
          acc[mi][ni] = __builtin_amdgcn_mfma_f32_16x16x32_bf16(af[mi], bfr[ni], acc[mi][ni], 0,0,0);
      }
    }
    __syncthreads();
  }
  float* dst = FTP + (((size_t)p*2 + sig)*16 + b)*128*128;
  #pragma unroll
  for(int mi=0;mi<4;++mi){
    #pragma unroll
    for(int ni=0;ni<4;++ni){
      int row = mh + mi*16 + q*4;
      int col = nh + ni*16 + ml;
      #pragma unroll
      for(int r=0;r<4;++r)
        dst[(size_t)(row+r)*128 + col] = acc[mi][ni][r];
    }
  }
}

// ---------------- deep VALU forward DFT (transposed input) -------------------
__global__ __launch_bounds__(256) void k_fwdeep(
    const bfu* __restrict__ dT, const bfu* __restrict__ sT,
    float* __restrict__ FTP, const float* __restrict__ TWc,
    int h, int l)
{
  int b = blockIdx.x, sig = blockIdx.y;
  const bfu* src = (sig? sT : dT) + (size_t)b*128*h;
  const float* TWs = TWc + (size_t)l*h;
  float* dst = FTP + ((size_t)sig*16 + b)*128*128;
  for(int idx = threadIdx.x; idx < l*128; idx += 256){
    int f = idx >> 7, ch = idx & 127;
    const bfu* row = src + (size_t)ch*h;
    const float* cr = TWc + (size_t)f*h;
    const float* sr = TWs + (size_t)f*h;
    float re=0.f, im=0.f;
    for(int t=0;t<h;++t){ float v = bs2f(row[t]); re += v*cr[t]; im -= v*sr[t]; }
    dst[(size_t)f*128 + ch] = re;
    dst[(size_t)(64+f)*128 + ch] = im;
  }
}

// ---------------- mode mixing: FTP -> YT[u][b][ch][f2] bf16 ------------------
__global__ __launch_bounds__(128) void k_modemixT(
    const float* __restrict__ FTP, const bfu* __restrict__ WT,
    bfu* __restrict__ YT, int h, int np)
{
  int f = blockIdx.x, b = blockIdx.y, o = threadIdx.x;
  __shared__ float sdr[128], sdi[128], ssr[128], ssi[128];
  {
    const size_t PS = (size_t)2*16*128*128;
    size_t r0 = ((size_t)b*128 + f)*128 + o;
    size_t r1 = r0 + (size_t)64*128;
    size_t r2 = r0 + (size_t)16*128*128;
    size_t r3 = r2 + (size_t)64*128;
    float ar=0, ai=0, br=0, bi=0;
    for(int p=0;p<np;++p){
      ar += FTP[r0 + (size_t)p*PS]; ai += FTP[r1 + (size_t)p*PS];
      br += FTP[r2 + (size_t)p*PS]; bi += FTP[r3 + (size_t)p*PS];
    }
    sdr[o]=ar; sdi[o]=ai; ssr[o]=br; ssi[o]=bi;
  }
  __syncthreads();
  const size_t WSZ = (size_t)64*128*128;
  float ydr=0, ydi=0, yur=0, yui=0;
  for(int i=0;i<128;++i){
    float dr=sdr[i], di=sdi[i], sr=ssr[i], si=ssi[i];
    size_t wb = ((size_t)f*128 + i)*128 + o;
    float Ar = bs2f(WT[wb]);
    float Ai = bs2f(WT[WSZ + wb]);
    float Br = bs2f(WT[2*WSZ + wb]);
    float Bi = bs2f(WT[3*WSZ + wb]);
    float Cr = bs2f(WT[4*WSZ + wb]);
    float Ci = bs2f(WT[5*WSZ + wb]);
    ydr += dr*Ar - di*Ai + sr*Br - si*Bi;
    ydi += dr*Ai + di*Ar + sr*Bi + si*Br;
    yur += dr*Cr - di*Ci;
    yui += dr*Ci + di*Cr;
  }
  float sc = 2.0f / (float)h;
  bool edge = (f==0) || (2*f == h);
  if(edge) sc = 1.0f / (float)h;
  size_t y0 = ((size_t)b*128 + o)*128;
  size_t y1 = y0 + (size_t)16*128*128;
  YT[y0 + f]      = f2bs(ydr*sc);
  YT[y0 + 64 + f] = edge ? (bfu)0 : f2bs(ydi*sc);
  YT[y1 + f]      = f2bs(yur*sc);
  YT[y1 + 64 + f] = edge ? (bfu)0 : f2bs(yui*sc);
}

// ---------------- MFMA inverse DFT: Ud/Us [b][t][ch] bf16 --------------------
__global__ __launch_bounds__(256) void k_invdft_mfma(
    const bfu* __restrict__ YT, const bfu* __restrict__ TWIl,
    bfu* __restrict__ Ud, bfu* __restrict__ Us, int h)
{
  int bx = blockIdx.x, b = blockIdx.y, u = blockIdx.z;
  bfu* outp = u ? Us : Ud;
  const bfu* Y = YT + ((size_t)u*16 + b)*128*128;
  int t0 = bx*128;
  __shared__ bfu lsA[128*136];
  __shared__ bfu lsB[128*136];
  int tid = threadIdx.x;
  #pragma unroll
  for(int it=0; it<8; ++it){
    int slot = it*256 + tid;
    int row = slot>>4, kq = slot&15;
    *reinterpret_cast<uint4*>(&lsA[row*136 + kq*8]) =
      *reinterpret_cast<const uint4*>(&TWIl[(size_t)(t0+row)*128 + kq*8]);
    *reinterpret_cast<uint4*>(&lsB[row*136 + kq*8]) =
      *reinterpret_cast<const uint4*>(&Y[(size_t)row*128 + kq*8]);
  }
  __syncthreads();
  int wave = tid>>6, lane = tid&63;
  int mh = (wave>>1)*64, nh = (wave&1)*64;
  int ml = lane&15, q = lane>>4;
  f32x4 acc[4][4];
  #pragma unroll
  for(int i=0;i<4;++i){
    #pragma unroll
    for(int j=0;j<4;++j) acc[i][j] = (f32x4)0.f;
  }
  #pragma unroll
  for(int kk=0; kk<128; kk+=32){
    bf16x8 af[4], bfr[4];
    #pragma unroll
    for(int mi=0;mi<4;++mi)
      af[mi] = *reinterpret_cast<const bf16x8*>(&lsA[(mh+mi*16+ml)*136 + kk + q*8]);
    #pragma unroll
    for(int ni=0;ni<4;++ni)
      bfr[ni] = *reinterpret_cast<const bf16x8*>(&lsB[(nh+ni*16+ml)*136 + kk + q*8]);
    #pragma unroll
    for(int mi=0;mi<4;++mi){
      #pragma unroll
      for(int ni=0;ni<4;++ni)
        acc[mi][ni] = __builtin_amdgcn_mfma_f32_16x16x32_bf16(af[mi], bfr[ni], acc[mi][ni], 0,0,0);
    }
  }
  #pragma unroll
  for(int mi=0;mi<4;++mi){
    #pragma unroll
    for(int ni=0;ni<4;++ni){
      int row = mh + mi*16 + q*4;
      int col = nh + ni*16 + ml;
      #pragma unroll
      for(int r=0;r<4;++r)
        outp[((size_t)b*h + t0+row+r)*128 + col] = f2bs(acc[mi][ni][r]);
    }
  }
}

// ---------------- deep VALU inverse DFT --------------------------------------
__global__ __launch_bounds__(256) void k_invdeep(
    const bfu* __restrict__ YT, bfu* __restrict__ Ud, bfu* __restrict__ Us,
    const float* __restrict__ TWc, int h, int l)
{
  int b = blockIdx.x, u = blockIdx.y;
  bfu* outp = (u? Us : Ud);
  const float* TWs = TWc + (size_t)l*h;
  for(int idx = threadIdx.x; idx < h*128; idx += 256){
    int t = idx >> 7, ch = idx & 127;
    const bfu* yrow = YT + (((size_t)u*16 + b)*128 + ch)*128;
    float a = 0.f;
    for(int f=0; f<l; ++f)
      a += bs2f(yrow[f])*TWc[(size_t)f*h + t] - bs2f(yrow[64+f])*TWs[(size_t)f*h + t];
    outp[((size_t)b*h + t)*128 + ch] = f2bs(a);
  }
}

// ---------------- LayerNorm + exact GELU on (16,1,128) -----------------------
__global__ __launch_bounds__(128) void k_lngelu(
    const bfu* __restrict__ xin, const bfu* __restrict__ CSM, bfu* __restrict__ xout)
{
  int b = blockIdx.x, tid = threadIdx.x;
  float v = bs2f(xin[b*128 + tid]);
  float s1 = v, s2 = v*v;
  #pragma unroll
  for(int o=32; o; o>>=1){ s1 += __shfl_down(s1,o); s2 += __shfl_down(s2,o); }
  __shared__ float red[2][2];
  int w = tid >> 6;
  if((tid & 63) == 0){ red[w][0]=s1; red[w][1]=s2; }
  __syncthreads();
  float m  = (red[0][0]+red[1][0]) * (1.0f/128.0f);
  float ms = (red[0][1]+red[1][1]) * (1.0f/128.0f);
  float var = ms - m*m;
  float xn = (v - m) * rsqrtf(var + 1e-5f) * bs2f(CSM[512+tid]) + bs2f(CSM[640+tid]);
  float g = 0.5f * xn * (1.0f + erff(xn * 0.70710678118654752f));
  xout[b*128 + tid] = f2bs(g);
}

// ---------------- reconstruction step ([t][ch] layout) -----------------------
__global__ __launch_bounds__(256) void k_recon(
    const bfu* __restrict__ xin, const bfu* __restrict__ usp, const bfu* __restrict__ udp,
    const bfu* __restrict__ CSM, void* __restrict__ xout, int h, int logh,
    int is_final, const int* __restrict__ FLAG)
{
  int f32 = is_final ? FLAG[0] : 0;
  __shared__ float Fe[16][8], Fo[16][8];
  int tid = threadIdx.x;
  if(tid < 128){ Fe[tid>>3][tid&7] = bs2f(CSM[256+tid]); Fo[tid>>3][tid&7] = bs2f(CSM[384+tid]); }
  __syncthreads();
  int idx = blockIdx.x*256 + tid;
  if(idx >= 16*h*16) return;
  int c  = idx & 15;
  int bt = idx >> 4;
  int t  = bt & (h-1);
  int b  = bt >> logh;
  size_t base = (((size_t)bt) << 7) + (c<<3);
  union{ uint4 u; bfu x[8]; } X, U, D;
  X.u = *reinterpret_cast<const uint4*>(xin + base);
  U.u = *reinterpret_cast<const uint4*>(usp + base);
  D.u = *reinterpret_cast<const uint4*>(udp + base);
  float y[16];
  #pragma unroll
  for(int j=0;j<8;++j){ y[j] = bs2f(X.x[j]) + bs2f(U.x[j]); y[8+j] = bs2f(D.x[j]); }
  float e8[8] = {0,0,0,0,0,0,0,0}, o8[8] = {0,0,0,0,0,0,0,0};
  #pragma unroll
  for(int j=0;j<16;++j){
    float v = y[j];
    #pragma unroll
    for(int k=0;k<8;++k){ e8[k] += v*Fe[j][k]; o8[k] += v*Fo[j][k]; }
  }
  size_t ob = (((size_t)(b*(h<<1) + (t<<1))) << 7) + (c<<3);
  if(f32){
    float* po = (float*)xout;
    *reinterpret_cast<float4*>(po + ob)       = make_float4(e8[0],e8[1],e8[2],e8[3]);
    *reinterpret_cast<float4*>(po + ob + 4)   = make_float4(e8[4],e8[5],e8[6],e8[7]);
    *reinterpret_cast<float4*>(po + ob + 128) = make_float4(o8[0],o8[1],o8[2],o8[3]);
    *reinterpret_cast<float4*>(po + ob + 132) = make_float4(o8[4],o8[5],o8[6],o8[7]);
  } else {
    union{ uint4 u; bfu x[8]; } Oe, Oo;
    #pragma unroll
    for(int k=0;k<8;++k){ Oe.x[k] = f2bs(e8[k]); Oo.x[k] = f2bs(o8[k]); }
    bfu* po = (bfu*)xout;
    *reinterpret_cast<uint4*>(po + ob)       = Oe.u;
    *reinterpret_cast<uint4*>(po + ob + 128) = Oo.u;
  }
}

// ============================================================================
extern "C" void kernel_launch(void* const* d_in, const int* in_sizes, int n_in,
                              void* d_out, int out_size, void* d_ws, size_t ws_size,
                              hipStream_t stream)
{
  (void)in_sizes; (void)n_in; (void)out_size; (void)ws_size;
  const void* x0 = d_in[0];
  WPtrs wp;
  for(int w=0;w<6;++w) wp.p[w] = d_in[1+w];

  char* ws = (char*)d_ws;
  size_t off = 0;
  auto carve = [&](size_t bytes)->char*{
    char* p = ws + off; off += (bytes + 255) & ~(size_t)255; return p; };

  int* FLAG = (int*)carve(256);
  bfu* CSM  = (bfu*)carve(2048);
  bfu* SA   = (bfu*)carve((size_t)16*4096*128*2);   // sT even levels
  bfu* SB   = (bfu*)carve((size_t)16*2048*128*2);   // sT odd levels
  bfu *Ud[13], *Us[13];
  for(int i=0;i<13;++i) Ud[i] = (bfu*)carve((size_t)16*(4096>>i)*128*2);
  for(int i=0;i<13;++i) Us[i] = (bfu*)carve((size_t)16*(4096>>i)*128*2);
  bfu*   Dscr = (bfu*)carve((size_t)16*4096*128*2);       // 16 MiB dT scratch
  float* FTP  = (float*)carve((size_t)16*2*16*128*128*4); // 32 MiB partials (np<=16)
  bfu*   YT   = (bfu*)carve((size_t)2*16*128*128*2);      // 1 MiB
  bfu*   WT   = (bfu*)carve((size_t)6*64*128*128*2);
  bfu*   TWF  = (bfu*)carve((size_t)1032192*2);
  bfu*   TWI  = (bfu*)carve((size_t)1032192*2);
  bfu*   XA   = Dscr;              // recon ping-pong (reuse, post-spectral)
  bfu*   XB   = (bfu*)FTP;

  // level params
  int hv[13], lv2[13];
  const int offF[6] = {0,524288,786432,917504,983040,1015808};
  for(int i=0;i<13;++i){
    int h = 4096 >> i;
    int l = (h/2+1) < 64 ? (h/2+1) : 64;
    hv[i]=h; lv2[i]=l;
  }
  // deep fp32 twiddles (levels 6..12)
  LevelTab lt;
  int acc = 0;
  for(int j=0;j<7;++j){
    int i = 6+j;
    lt.twoff[j]=acc; lt.ll[j]=lv2[i]; lt.logh[j]=12-i;
    acc += 2*lv2[i]*hv[i];
  }
  for(int j=7;j<13;++j){ lt.twoff[j]=0; lt.ll[j]=1; lt.logh[j]=0; }
  float* TWD = (float*)carve((size_t)acc*4);

  k_sniff<<<dim3(1),256,0,stream>>>((const bfu*)x0, FLAG);
  k_cvt_small<<<dim3(1),256,0,stream>>>(d_in[7], d_in[8], d_in[9], d_in[10], d_in[11], d_in[12], CSM, FLAG);
  k_wtrans<<<dim3(2,128,6),64,0,stream>>>(wp, WT, FLAG);
  k_twgenF<<<dim3(4032,2),256,0,stream>>>(TWF, TWI);
  k_twgen<<<dim3(17,7),256,0,stream>>>(lt, TWD);

  bfu* ST[13];
  for(int i=0;i<13;++i) ST[i] = (i&1) ? SB : SA;

  // levels 0..5: MFMA path
  for(int i=0;i<6;++i){
    int h = hv[i];
    int np = (h/64 < 16) ? (h/64) : 16;
    int Kpart = h/np;
    if(i==0){
      k_decomp0<<<dim3(h/32,16),256,0,stream>>>(x0, Dscr, ST[0], CSM, h, FLAG);
    } else {
      int total = 16*16*(h>>2);
      k_decompT<<<dim3((total+255)/256),256,0,stream>>>(ST[i-1], Dscr, ST[i], CSM, h, total);
    }
    k_fwdft_mfma<<<dim3(np,16,2),256,0,stream>>>(Dscr, ST[i], TWF + offF[i], FTP, h, Kpart);
    k_modemixT<<<dim3(64,16),128,0,stream>>>(FTP, WT, YT, h, np);
    k_invdft_mfma<<<dim3(h/128,16,2),256,0,stream>>>(YT, TWI + offF[i], Ud[i], Us[i], h);
  }
  // levels 6..12: VALU path (transposed layouts)
  for(int i=6;i<13;++i){
    int h = hv[i], l = lv2[i];
    int total = (h>=4) ? 16*16*(h>>2) : 256;
    k_decompT<<<dim3((total+255)/256),256,0,stream>>>(ST[i-1], Dscr, ST[i], CSM, h, total);
    const float* cT = TWD + lt.twoff[i-6];
    k_fwdeep<<<dim3(16,2),256,0,stream>>>(Dscr, ST[i], FTP, cT, h, l);
    k_modemixT<<<dim3(l,16),128,0,stream>>>(FTP, WT, YT, h, 1);
    k_invdeep<<<dim3(16,2),256,0,stream>>>(YT, Ud[i], Us[i], cT, h, l);
  }
  k_lngelu<<<dim3(16),128,0,stream>>>(ST[12], CSM, XA);
  bfu* rin = XA;
  for(int i=12;i>=0;--i){
    int h = hv[i];
    void* rout = (i==0) ? d_out : (void*)((rin==XA) ? XB : XA);
    int tot = 16*h*16;
    k_recon<<<dim3((tot+255)/256),256,0,stream>>>(rin, Us[i], Ud[i], CSM, rout, h, 12-i, (i==0)?1:0, FLAG);
    rin = (bfu*)rout;
  }
}

// Round 4
// 1016.643 us; speedup vs baseline: 1.4974x; 1.4472x over previous
//
#include <hip/hip_runtime.h>
#include <math.h>

typedef unsigned short bfu;   // raw bf16 bits
typedef short bf16x8 __attribute__((ext_vector_type(8)));
typedef float f32x4 __attribute__((ext_vector_type(4)));

__device__ __forceinline__ float bs2f(bfu s){
  union{ unsigned int u; float f; } v; v.u = ((unsigned int)s) << 16; return v.f;
}
__device__ __forceinline__ bfu f2bs(float f){
  union{ float ff; unsigned int u; } v; v.ff = f;
  unsigned int u = v.u;
  unsigned int r = (u + 0x7fffu + ((u >> 16) & 1u)) >> 16;   // RNE
  return (bfu)r;
}

struct LevelTab { int twoff[13]; int ll[13]; int logh[13]; };
struct WPtrs { const void* p[6]; };

// ---------------- dtype sniff ------------------------------------------------
__global__ __launch_bounds__(256) void k_sniff(const bfu* __restrict__ x, int* __restrict__ flag){
  __shared__ int cnt;
  if(threadIdx.x==0) cnt = 0;
  __syncthreads();
  int c = 0;
  for(int j=threadIdx.x; j<4096; j+=256){
    bfu v = x[2*j];
    int e = (v>>7)&0xFF;
    if(e >= 0xC0) c++;
  }
  atomicAdd(&cnt, c);
  __syncthreads();
  if(threadIdx.x==0) flag[0] = (cnt > 64) ? 1 : 0;
}

// ---------------- small arrays -> bf16. 0=ec_s,128=ec_d,256=rc_e,384=rc_o,512=ln_w,640=ln_b
__global__ __launch_bounds__(256) void k_cvt_small(
    const void* lnw, const void* lnb, const void* ecs, const void* ecd,
    const void* rce, const void* rco, bfu* __restrict__ CSM, const int* __restrict__ FLAG){
  int f32 = FLAG[0];
  const void* src[6] = {ecs, ecd, rce, rco, lnw, lnb};
  int tid = threadIdx.x;
  for(int a=0; a<6; ++a)
    for(int j=tid; j<128; j+=256)
      CSM[a*128+j] = f32 ? f2bs(((const float*)src[a])[j]) : ((const bfu*)src[a])[j];
}

// ---------------- weight transpose: W[i][o][f] -> T[f][i][o], bf16 -----------
__global__ __launch_bounds__(64) void k_wtrans(WPtrs wp, bfu* __restrict__ T, const int* __restrict__ FLAG){
  int f32 = FLAG[0];
  int o = blockIdx.x*64 + threadIdx.x;
  int i = blockIdx.y;
  int w = blockIdx.z;
  size_t sb = ((size_t)i*128 + o)*64;
  bfu* dst = T + (size_t)w*64*128*128;
  #pragma unroll 4
  for(int f=0; f<64; ++f){
    bfu v = f32 ? f2bs(((const float*)wp.p[w])[sb+f]) : ((const bfu*)wp.p[w])[sb+f];
    dst[((size_t)f*128 + i)*128 + o] = v;
  }
}

// ---------------- bf16 twiddle matrices for MFMA levels 0..5 -----------------
// TWF[level]: [r(128)][t(h)] ; r<64: cos(2*pi*r*t/h), r>=64: -sin(2*pi*(r-64)*t/h)
// TWI[level]: [t(h)][f2(128)]; f2<64: cos, f2>=64: -sin
__global__ __launch_bounds__(256) void k_twgenF(bfu* __restrict__ TWF, bfu* __restrict__ TWI){
  int e = blockIdx.x*256 + threadIdx.x;      // 0..1032191
  int kind = blockIdx.y;
  const int offs[7] = {0,524288,786432,917504,983040,1015808,1032192};
  int le = 5;
  #pragma unroll
  for(int i=0;i<6;++i){ if(e < offs[i+1]){ le = i; break; } }
  int rem = e - offs[le];
  int logh = 12 - le;
  int h = 1 << logh;
  int f, t, neg;
  if(kind==0){ int r = rem >> logh; t = rem & (h-1); f = (r<64)?r:(r-64); neg = (r>=64); }
  else       { t = rem >> 7; int f2 = rem & 127;     f = (f2<64)?f2:(f2-64); neg = (f2>=64); }
  int m = (f*t) & (h-1);
  float th = 6.283185307179586f * ((float)m / (float)h);
  float s, c; sincosf(th, &s, &c);
  float val = neg ? -s : c;
  if(kind==0) TWF[e] = f2bs(val); else TWI[e] = f2bs(val);
}

// ---------------- fp32 twiddles for deep levels (cos at [f*h+t], sin after l*h)
__global__ __launch_bounds__(256) void k_twgen(LevelTab lt, float* __restrict__ tw){
  int lev = blockIdx.y;
  int logh = lt.logh[lev];
  int h = 1 << logh;
  int l = lt.ll[lev];
  int tot = l*h;
  int idx = blockIdx.x*256 + threadIdx.x;
  if(idx >= tot) return;
  int t = idx & (h-1);
  int f = idx >> logh;
  int m = (f*t) & (h-1);
  float th = 6.283185307179586f * ((float)m / (float)h);
  float s, c; sincosf(th, &s, &c);
  tw[lt.twoff[lev] + idx] = c;
  tw[lt.twoff[lev] + tot + idx] = s;
}

// ---------------- level-0 decompose: x (B,2h,128) row-major -> dT,sT [b][ch][h]
__global__ __launch_bounds__(256) void k_decomp0(
    const void* __restrict__ xin, bfu* __restrict__ dT, bfu* __restrict__ sT,
    const bfu* __restrict__ CSM, int h, const int* __restrict__ FLAG)
{
  int f32 = FLAG[0];
  __shared__ float ls[64][132];
  __shared__ float Fd[16][8], Fs[16][8];
  int tid = threadIdx.x;
  if(tid < 128){ Fs[tid>>3][tid&7] = bs2f(CSM[tid]); Fd[tid>>3][tid&7] = bs2f(CSM[128+tid]); }
  int b = blockIdx.y;
  int t0in = blockIdx.x * 64;
  if(f32){
    const float* src = (const float*)xin + ((size_t)b*2*h + t0in)*128;
    #pragma unroll
    for(int it=0; it<8; ++it){
      int e = it*256 + tid;
      int row = e>>5, cq = e&31;
      float4 v = *reinterpret_cast<const float4*>(src + (size_t)row*128 + cq*4);
      ls[row][cq*4+0]=v.x; ls[row][cq*4+1]=v.y; ls[row][cq*4+2]=v.z; ls[row][cq*4+3]=v.w;
    }
  } else {
    const bfu* src = (const bfu*)xin + ((size_t)b*2*h + t0in)*128;
    #pragma unroll
    for(int it=0; it<4; ++it){
      int e = it*256 + tid;
      int row = e>>4, cq = e&15;
      union{uint4 u; bfu x[8];} U;
      U.u = *reinterpret_cast<const uint4*>(src + (size_t)row*128 + cq*8);
      #pragma unroll
      for(int j=0;j<8;++j) ls[row][cq*8+j] = bs2f(U.x[j]);
    }
  }
  __syncthreads();
  int g = tid>>7, ch = tid&127;
  int c = ch>>3, kp = ch&7;
  float fdE[8], fdO[8], fsE[8], fsO[8];
  #pragma unroll
  for(int j=0;j<8;++j){ fdE[j]=Fd[j][kp]; fdO[j]=Fd[8+j][kp]; fsE[j]=Fs[j][kp]; fsO[j]=Fs[8+j][kp]; }
  union{ uint4 u[2]; bfu x[16]; } OD, OS;
  #pragma unroll
  for(int tl=0; tl<16; ++tl){
    int rl = 2*(g*16+tl);
    const float* ev = &ls[rl][c*8];
    const float* od = &ls[rl+1][c*8];
    float d=0.f, s=0.f;
    #pragma unroll
    for(int j=0;j<8;++j){
      d += ev[j]*fdE[j] + od[j]*fdO[j];
      s += ev[j]*fsE[j] + od[j]*fsO[j];
    }
    OD.x[tl] = f2bs(d); OS.x[tl] = f2bs(s);
  }
  size_t obase = ((size_t)b*128 + ch)*h + (size_t)(t0in>>1) + g*16;
  *reinterpret_cast<uint4*>(dT + obase)     = OD.u[0];
  *reinterpret_cast<uint4*>(dT + obase + 8) = OD.u[1];
  *reinterpret_cast<uint4*>(sT + obase)     = OS.u[0];
  *reinterpret_cast<uint4*>(sT + obase + 8) = OS.u[1];
}

// ---------------- transposed decompose (levels >=1): inT [b][ch][2h] -> dT,sT [b][ch][h]
__global__ __launch_bounds__(256) void k_decompT(
    const bfu* __restrict__ inT, bfu* __restrict__ dT, bfu* __restrict__ sT,
    const bfu* __restrict__ CSM, int h, int total)
{
  __shared__ float Fd[16][8], Fs[16][8];
  int tid = threadIdx.x;
  if(tid < 128){ Fs[tid>>3][tid&7] = bs2f(CSM[tid]); Fd[tid>>3][tid&7] = bs2f(CSM[128+tid]); }
  __syncthreads();
  int idx = blockIdx.x*256 + tid;
  if(idx >= total) return;
  if(h >= 4){
    int nto = h>>2;
    int to = idx & (nto-1);
    int bc = idx / nto;
    int c = bc & 15, b = bc >> 4;
    const bfu* base = inT + ((size_t)b*128 + c*8)*(size_t)(2*h) + to*8;
    float d8[4][8] = {}, s8[4][8] = {};
    #pragma unroll
    for(int k=0;k<8;++k){
      union{uint4 u; bfu x[8];} U;
      U.u = *reinterpret_cast<const uint4*>(base + (size_t)k*(2*h));
      const float* fdE = Fd[k]; const float* fdO = Fd[8+k];
      const float* fsE = Fs[k]; const float* fsO = Fs[8+k];
      #pragma unroll
      for(int tl=0; tl<4; ++tl){
        float ev = bs2f(U.x[2*tl]), od = bs2f(U.x[2*tl+1]);
        #pragma unroll
        for(int kp=0;kp<8;++kp){
          d8[tl][kp] += ev*fdE[kp] + od*fdO[kp];
          s8[tl][kp] += ev*fsE[kp] + od*fsO[kp];
        }
      }
    }
    #pragma unroll
    for(int kp=0;kp<8;++kp){
      union{uint2 u; bfu x[4];} Od, Os;
      #pragma unroll
      for(int tl=0;tl<4;++tl){ Od.x[tl]=f2bs(d8[tl][kp]); Os.x[tl]=f2bs(s8[tl][kp]); }
      size_t ob = ((size_t)b*128 + c*8 + kp)*h + to*4;
      *reinterpret_cast<uint2*>(dT + ob) = Od.u;
      *reinterpret_cast<uint2*>(sT + ob) = Os.u;
    }
  } else {
    int c = idx & 15, b = idx >> 4;
    const bfu* base = inT + ((size_t)b*128 + c*8)*(size_t)(2*h);
    for(int tl=0; tl<h; ++tl){
      float d8[8]={}, s8[8]={};
      for(int k=0;k<8;++k){
        float ev = bs2f(base[(size_t)k*2*h + 2*tl]);
        float od = bs2f(base[(size_t)k*2*h + 2*tl+1]);
        #pragma unroll
        for(int kp=0;kp<8;++kp){
          d8[kp] += ev*Fd[k][kp] + od*Fd[8+k][kp];
          s8[kp] += ev*Fs[k][kp] + od*Fs[8+k][kp];
        }
      }
      for(int kp=0;kp<8;++kp){
        size_t ob = ((size_t)b*128 + c*8 + kp)*h + tl;
        dT[ob] = f2bs(d8[kp]); sT[ob] = f2bs(s8[kp]);
      }
    }
  }
}

// ---------------- MFMA forward DFT: FTP[p][sig][b][row(128)][ch(128)] fp32 ---
__global__ __launch_bounds__(256) void k_fwdft_mfma(
    const bfu* __restrict__ dT, const bfu* __restrict__ sT,
    const bfu* __restrict__ TWFl, float* __restrict__ FTP,
    int h, int Kpart)
{
  int p = blockIdx.x, b = blockIdx.y, sig = blockIdx.z;
  const bfu* SIG = (sig ? sT : dT) + (size_t)b*128*h;
  __shared__ bfu lsA[128*72];
  __shared__ bfu lsB[128*72];
  int tid = threadIdx.x;
  int wave = tid>>6, lane = tid&63;
  int mh = (wave>>1)*64, nh = (wave&1)*64;
  int ml = lane&15, q = lane>>4;
  f32x4 acc[4][4];
  #pragma unroll
  for(int i=0;i<4;++i){
    #pragma unroll
    for(int j=0;j<4;++j) acc[i][j] = (f32x4)0.f;
  }
  int k0base = p*Kpart;
  for(int kc=0; kc<Kpart; kc+=64){
    int k0 = k0base + kc;
    #pragma unroll
    for(int it=0; it<4; ++it){
      int slot = it*256 + tid;
      int row = slot>>3, kq = slot&7;
      *reinterpret_cast<uint4*>(&lsA[row*72 + kq*8]) =
        *reinterpret_cast<const uint4*>(&TWFl[(size_t)row*h + k0 + kq*8]);
      *reinterpret_cast<uint4*>(&lsB[row*72 + kq*8]) =
        *reinterpret_cast<const uint4*>(&SIG[(size_t)row*h + k0 + kq*8]);
    }
    __syncthreads();
    #pragma unroll
    for(int kk=0; kk<64; kk+=32){
      bf16x8 af[4], bfr[4];
      #pragma unroll
      for(int mi=0;mi<4;++mi)
        af[mi] = *reinterpret_cast<const bf16x8*>(&lsA[(mh+mi*16+ml)*72 + kk + q*8]);
      #pragma unroll
      for(int ni=0;ni<4;++ni)
        bfr[ni] = *reinterpret_cast<const bf16x8*>(&lsB[(nh+ni*16+ml)*72 + kk + q*8]);
      #pragma unroll
      for(int mi=0;mi<4;++mi){
        #pragma unroll
        for(int ni=0;ni<4;++ni)
          acc[mi][ni] = __builtin_amdgcn_mfma_f32_16x16x32_bf16(af[mi], bfr[ni], acc[mi][ni], 0,0,0);
      }
    }
    __syncthreads();
  }
  float* dst = FTP + (((size_t)p*2 + sig)*16 + b)*128*128;
  #pragma unroll
  for(int mi=0;mi<4;++mi){
    #pragma unroll
    for(int ni=0;ni<4;++ni){
      int row = mh + mi*16 + q*4;
      int col = nh + ni*16 + ml;
      #pragma unroll
      for(int r=0;r<4;++r)
        dst[(size_t)(row+r)*128 + col] = acc[mi][ni][r];
    }
  }
}

// ---------------- deep forward DFT, LDS-resident -----------------------------
// grid (16, 2) block 256. out rows: re at f, im at 64+f.  h<=64, l<=33.
__global__ __launch_bounds__(256) void k_fwdeep2(
    const bfu* __restrict__ dT, const bfu* __restrict__ sT,
    float* __restrict__ FTP, const float* __restrict__ TWc,
    int h, int l, int logh)
{
  int b = blockIdx.x, sig = blockIdx.y;
  const bfu* src = (sig? sT : dT) + (size_t)b*128*h;
  float* dst = FTP + ((size_t)sig*16 + b)*128*128;
  __shared__ float s_sig[128*65];        // [ch][h] pad stride h+1
  __shared__ float s_twc[33*64];
  __shared__ float s_tws[33*64];
  int tid = threadIdx.x;
  int hp = h + 1;
  for(int e = tid; e < 128*h; e += 256){
    int ch = e >> logh, t = e & (h-1);
    s_sig[ch*hp + t] = bs2f(src[e]);
  }
  int lh = l*h;
  const float* TWs = TWc + (size_t)lh;
  for(int e = tid; e < lh; e += 256){ s_twc[e] = TWc[e]; s_tws[e] = TWs[e]; }
  __syncthreads();
  for(int idx = tid; idx < l*128; idx += 256){
    int f = idx >> 7, ch = idx & 127;
    const float* sp = &s_sig[ch*hp];
    const float* cp = &s_twc[f*h];
    const float* zp = &s_tws[f*h];
    float re = 0.f, im = 0.f;
    for(int t=0; t<h; ++t){ float v = sp[t]; re += v*cp[t]; im -= v*zp[t]; }
    dst[(size_t)f*128 + ch] = re;
    dst[(size_t)(64+f)*128 + ch] = im;
  }
}

// ---------------- mode mixing: FTP -> YT[u][b][ch][f2] bf16 ------------------
__global__ __launch_bounds__(128) void k_modemixT(
    const float* __restrict__ FTP, const bfu* __restrict__ WT,
    bfu* __restrict__ YT, int h, int np)
{
  int f = blockIdx.x, b = blockIdx.y, o = threadIdx.x;
  __shared__ float sdr[128], sdi[128], ssr[128], ssi[128];
  {
    const size_t PS = (size_t)2*16*128*128;
    size_t r0 = ((size_t)b*128 + f)*128 + o;
    size_t r1 = r0 + (size_t)64*128;
    size_t r2 = r0 + (size_t)16*128*128;
    size_t r3 = r2 + (size_t)64*128;
    float ar=0, ai=0, br=0, bi=0;
    for(int p=0;p<np;++p){
      ar += FTP[r0 + (size_t)p*PS]; ai += FTP[r1 + (size_t)p*PS];
      br += FTP[r2 + (size_t)p*PS]; bi += FTP[r3 + (size_t)p*PS];
    }
    sdr[o]=ar; sdi[o]=ai; ssr[o]=br; ssi[o]=bi;
  }
  __syncthreads();
  const size_t WSZ = (size_t)64*128*128;
  float ydr=0, ydi=0, yur=0, yui=0;
  for(int i=0;i<128;++i){
    float dr=sdr[i], di=sdi[i], sr=ssr[i], si=ssi[i];
    size_t wb = ((size_t)f*128 + i)*128 + o;
    float Ar = bs2f(WT[wb]);
    float Ai = bs2f(WT[WSZ + wb]);
    float Br = bs2f(WT[2*WSZ + wb]);
    float Bi = bs2f(WT[3*WSZ + wb]);
    float Cr = bs2f(WT[4*WSZ + wb]);
    float Ci = bs2f(WT[5*WSZ + wb]);
    ydr += dr*Ar - di*Ai + sr*Br - si*Bi;
    ydi += dr*Ai + di*Ar + sr*Bi + si*Br;
    yur += dr*Cr - di*Ci;
    yui += dr*Ci + di*Cr;
  }
  float sc = 2.0f / (float)h;
  bool edge = (f==0) || (2*f == h);
  if(edge) sc = 1.0f / (float)h;
  size_t y0 = ((size_t)b*128 + o)*128;
  size_t y1 = y0 + (size_t)16*128*128;
  YT[y0 + f]      = f2bs(ydr*sc);
  YT[y0 + 64 + f] = edge ? (bfu)0 : f2bs(ydi*sc);
  YT[y1 + f]      = f2bs(yur*sc);
  YT[y1 + 64 + f] = edge ? (bfu)0 : f2bs(yui*sc);
}

// ---------------- MFMA inverse DFT: Ud/Us [b][t][ch] bf16 --------------------
__global__ __launch_bounds__(256) void k_invdft_mfma(
    const bfu* __restrict__ YT, const bfu* __restrict__ TWIl,
    bfu* __restrict__ Ud, bfu* __restrict__ Us, int h)
{
  int bx = blockIdx.x, b = blockIdx.y, u = blockIdx.z;
  bfu* outp = u ? Us : Ud;
  const bfu* Y = YT + ((size_t)u*16 + b)*128*128;
  int t0 = bx*128;
  __shared__ bfu lsA[128*136];
  __shared__ bfu lsB[128*136];
  int tid = threadIdx.x;
  #pragma unroll
  for(int it=0; it<8; ++it){
    int slot = it*256 + tid;
    int row = slot>>4, kq = slot&15;
    *reinterpret_cast<uint4*>(&lsA[row*136 + kq*8]) =
      *reinterpret_cast<const uint4*>(&TWIl[(size_t)(t0+row)*128 + kq*8]);
    *reinterpret_cast<uint4*>(&lsB[row*136 + kq*8]) =
      *reinterpret_cast<const uint4*>(&Y[(size_t)row*128 + kq*8]);
  }
  __syncthreads();
  int wave = tid>>6, lane = tid&63;
  int mh = (wave>>1)*64, nh = (wave&1)*64;
  int ml = lane&15, q = lane>>4;
  f32x4 acc[4][4];
  #pragma unroll
  for(int i=0;i<4;++i){
    #pragma unroll
    for(int j=0;j<4;++j) acc[i][j] = (f32x4)0.f;
  }
  #pragma unroll
  for(int kk=0; kk<128; kk+=32){
    bf16x8 af[4], bfr[4];
    #pragma unroll
    for(int mi=0;mi<4;++mi)
      af[mi] = *reinterpret_cast<const bf16x8*>(&lsA[(mh+mi*16+ml)*136 + kk + q*8]);
    #pragma unroll
    for(int ni=0;ni<4;++ni)
      bfr[ni] = *reinterpret_cast<const bf16x8*>(&lsB[(nh+ni*16+ml)*136 + kk + q*8]);
    #pragma unroll
    for(int mi=0;mi<4;++mi){
      #pragma unroll
      for(int ni=0;ni<4;++ni)
        acc[mi][ni] = __builtin_amdgcn_mfma_f32_16x16x32_bf16(af[mi], bfr[ni], acc[mi][ni], 0,0,0);
    }
  }
  #pragma unroll
  for(int mi=0;mi<4;++mi){
    #pragma unroll
    for(int ni=0;ni<4;++ni){
      int row = mh + mi*16 + q*4;
      int col = nh + ni*16 + ml;
      #pragma unroll
      for(int r=0;r<4;++r)
        outp[((size_t)b*h + t0+row+r)*128 + col] = f2bs(acc[mi][ni][r]);
    }
  }
}

// ---------------- deep inverse DFT, LDS-resident -----------------------------
// grid (16, 2) block 256. YT[u][b][ch][128]: re f<l at [f], im at [64+f].
__global__ __launch_bounds__(256) void k_invdeep2(
    const bfu* __restrict__ YT, bfu* __restrict__ Ud, bfu* __restrict__ Us,
    const float* __restrict__ TWc, int h, int l)
{
  int b = blockIdx.x, u = blockIdx.y;
  bfu* outp = (u? Us : Ud) + (size_t)b*h*128;
  const bfu* Y = YT + ((size_t)u*16 + b)*128*128;
  __shared__ float s_yr[128*66];   // [ch][64] pad stride 66
  __shared__ float s_yi[128*66];
  __shared__ float s_twc[33*64];
  __shared__ float s_tws[33*64];
  int tid = threadIdx.x;
  #pragma unroll
  for(int it=0; it<8; ++it){
    int slot = it*256 + tid;          // 2048 uint4 slots cover [128][128] bf16
    int ch = slot >> 4, kq = slot & 15;
    union{uint4 u4; bfu x[8];} U;
    U.u4 = *reinterpret_cast<const uint4*>(&Y[(size_t)ch*128 + kq*8]);
    if(kq < 8){
      #pragma unroll
      for(int j=0;j<8;++j) s_yr[ch*66 + kq*8 + j] = bs2f(U.x[j]);
    } else {
      #pragma unroll
      for(int j=0;j<8;++j) s_yi[ch*66 + (kq-8)*8 + j] = bs2f(U.x[j]);
    }
  }
  int lh = l*h;
  const float* TWs = TWc + (size_t)lh;
  for(int e = tid; e < lh; e += 256){ s_twc[e] = TWc[e]; s_tws[e] = TWs[e]; }
  __syncthreads();
  for(int idx = tid; idx < h*128; idx += 256){
    int t = idx >> 7, ch = idx & 127;
    const float* yr = &s_yr[ch*66];
    const float* yi = &s_yi[ch*66];
    float a = 0.f;
    for(int f=0; f<l; ++f)
      a += yr[f]*s_twc[f*h + t] - yi[f]*s_tws[f*h + t];
    outp[idx] = f2bs(a);
  }
}

// ---------------- LayerNorm + exact GELU on (16,1,128) -----------------------
__global__ __launch_bounds__(128) void k_lngelu(
    const bfu* __restrict__ xin, const bfu* __restrict__ CSM, bfu* __restrict__ xout)
{
  int b = blockIdx.x, tid = threadIdx.x;
  float v = bs2f(xin[b*128 + tid]);
  float s1 = v, s2 = v*v;
  #pragma unroll
  for(int o=32; o; o>>=1){ s1 += __shfl_down(s1,o); s2 += __shfl_down(s2,o); }
  __shared__ float red[2][2];
  int w = tid >> 6;
  if((tid & 63) == 0){ red[w][0]=s1; red[w][1]=s2; }
  __syncthreads();
  float m  = (red[0][0]+red[1][0]) * (1.0f/128.0f);
  float ms = (red[0][1]+red[1][1]) * (1.0f/128.0f);
  float var = ms - m*m;
  float xn = (v - m) * rsqrtf(var + 1e-5f) * bs2f(CSM[512+tid]) + bs2f(CSM[640+tid]);
  float g = 0.5f * xn * (1.0f + erff(xn * 0.70710678118654752f));
  xout[b*128 + tid] = f2bs(g);
}

// ---------------- reconstruction step ([t][ch] layout) -----------------------
__global__ __launch_bounds__(256) void k_recon(
    const bfu* __restrict__ xin, const bfu* __restrict__ usp, const bfu* __restrict__ udp,
    const bfu* __restrict__ CSM, void* __restrict__ xout, int h, int logh,
    int is_final, const int* __restrict__ FLAG)
{
  int f32 = is_final ? FLAG[0] : 0;
  __shared__ float Fe[16][8], Fo[16][8];
  int tid = threadIdx.x;
  if(tid < 128){ Fe[tid>>3][tid&7] = bs2f(CSM[256+tid]); Fo[tid>>3][tid&7] = bs2f(CSM[384+tid]); }
  __syncthreads();
  int idx = blockIdx.x*256 + tid;
  if(idx >= 16*h*16) return;
  int c  = idx & 15;
  int bt = idx >> 4;
  int t  = bt & (h-1);
  int b  = bt >> logh;
  size_t base = (((size_t)bt) << 7) + (c<<3);
  union{ uint4 u; bfu x[8]; } X, U, D;
  X.u = *reinterpret_cast<const uint4*>(xin + base);
  U.u = *reinterpret_cast<const uint4*>(usp + base);
  D.u = *reinterpret_cast<const uint4*>(udp + base);
  float y[16];
  #pragma unroll
  for(int j=0;j<8;++j){ y[j] = bs2f(X.x[j]) + bs2f(U.x[j]); y[8+j] = bs2f(D.x[j]); }
  float e8[8] = {0,0,0,0,0,0,0,0}, o8[8] = {0,0,0,0,0,0,0,0};
  #pragma unroll
  for(int j=0;j<16;++j){
    float v = y[j];
    #pragma unroll
    for(int k=0;k<8;++k){ e8[k] += v*Fe[j][k]; o8[k] += v*Fo[j][k]; }
  }
  size_t ob = (((size_t)(b*(h<<1) + (t<<1))) << 7) + (c<<3);
  if(f32){
    float* po = (float*)xout;
    *reinterpret_cast<float4*>(po + ob)       = make_float4(e8[0],e8[1],e8[2],e8[3]);
    *reinterpret_cast<float4*>(po + ob + 4)   = make_float4(e8[4],e8[5],e8[6],e8[7]);
    *reinterpret_cast<float4*>(po + ob + 128) = make_float4(o8[0],o8[1],o8[2],o8[3]);
    *reinterpret_cast<float4*>(po + ob + 132) = make_float4(o8[4],o8[5],o8[6],o8[7]);
  } else {
    union{ uint4 u; bfu x[8]; } Oe, Oo;
    #pragma unroll
    for(int k=0;k<8;++k){ Oe.x[k] = f2bs(e8[k]); Oo.x[k] = f2bs(o8[k]); }
    bfu* po = (bfu*)xout;
    *reinterpret_cast<uint4*>(po + ob)       = Oe.u;
    *reinterpret_cast<uint4*>(po + ob + 128) = Oo.u;
  }
}

// ============================================================================
extern "C" void kernel_launch(void* const* d_in, const int* in_sizes, int n_in,
                              void* d_out, int out_size, void* d_ws, size_t ws_size,
                              hipStream_t stream)
{
  (void)in_sizes; (void)n_in; (void)out_size; (void)ws_size;
  const void* x0 = d_in[0];
  WPtrs wp;
  for(int w=0;w<6;++w) wp.p[w] = d_in[1+w];

  char* ws = (char*)d_ws;
  size_t off = 0;
  auto carve = [&](size_t bytes)->char*{
    char* p = ws + off; off += (bytes + 255) & ~(size_t)255; return p; };

  int* FLAG = (int*)carve(256);
  bfu* CSM  = (bfu*)carve(2048);
  bfu* SA   = (bfu*)carve((size_t)16*4096*128*2);   // sT even levels
  bfu* SB   = (bfu*)carve((size_t)16*2048*128*2);   // sT odd levels
  bfu *Ud[13], *Us[13];
  for(int i=0;i<13;++i) Ud[i] = (bfu*)carve((size_t)16*(4096>>i)*128*2);
  for(int i=0;i<13;++i) Us[i] = (bfu*)carve((size_t)16*(4096>>i)*128*2);
  bfu*   Dscr = (bfu*)carve((size_t)16*4096*128*2);       // 16 MiB dT scratch
  float* FTP  = (float*)carve((size_t)16*2*16*128*128*4); // 32 MiB partials (np<=16)
  bfu*   YT   = (bfu*)carve((size_t)2*16*128*128*2);      // 1 MiB
  bfu*   WT   = (bfu*)carve((size_t)6*64*128*128*2);
  bfu*   TWF  = (bfu*)carve((size_t)1032192*2);
  bfu*   TWI  = (bfu*)carve((size_t)1032192*2);
  bfu*   XA   = Dscr;              // recon ping-pong (reuse, post-spectral)
  bfu*   XB   = (bfu*)FTP;

  // level params
  int hv[13], lv2[13];
  const int offF[6] = {0,524288,786432,917504,983040,1015808};
  for(int i=0;i<13;++i){
    int h = 4096 >> i;
    int l = (h/2+1) < 64 ? (h/2+1) : 64;
    hv[i]=h; lv2[i]=l;
  }
  // deep fp32 twiddles (levels 6..12)
  LevelTab lt;
  int acc = 0;
  for(int j=0;j<7;++j){
    int i = 6+j;
    lt.twoff[j]=acc; lt.ll[j]=lv2[i]; lt.logh[j]=12-i;
    acc += 2*lv2[i]*hv[i];
  }
  for(int j=7;j<13;++j){ lt.twoff[j]=0; lt.ll[j]=1; lt.logh[j]=0; }
  float* TWD = (float*)carve((size_t)acc*4);

  k_sniff<<<dim3(1),256,0,stream>>>((const bfu*)x0, FLAG);
  k_cvt_small<<<dim3(1),256,0,stream>>>(d_in[7], d_in[8], d_in[9], d_in[10], d_in[11], d_in[12], CSM, FLAG);
  k_wtrans<<<dim3(2,128,6),64,0,stream>>>(wp, WT, FLAG);
  k_twgenF<<<dim3(4032,2),256,0,stream>>>(TWF, TWI);
  k_twgen<<<dim3(17,7),256,0,stream>>>(lt, TWD);

  bfu* ST[13];
  for(int i=0;i<13;++i) ST[i] = (i&1) ? SB : SA;

  // levels 0..5: MFMA path
  for(int i=0;i<6;++i){
    int h = hv[i];
    int np = (h/64 < 16) ? (h/64) : 16;
    int Kpart = h/np;
    if(i==0){
      k_decomp0<<<dim3(h/32,16),256,0,stream>>>(x0, Dscr, ST[0], CSM, h, FLAG);
    } else {
      int total = 16*16*(h>>2);
      k_decompT<<<dim3((total+255)/256),256,0,stream>>>(ST[i-1], Dscr, ST[i], CSM, h, total);
    }
    k_fwdft_mfma<<<dim3(np,16,2),256,0,stream>>>(Dscr, ST[i], TWF + offF[i], FTP, h, Kpart);
    k_modemixT<<<dim3(64,16),128,0,stream>>>(FTP, WT, YT, h, np);
    k_invdft_mfma<<<dim3(h/128,16,2),256,0,stream>>>(YT, TWI + offF[i], Ud[i], Us[i], h);
  }
  // levels 6..12: LDS-resident deep path
  for(int i=6;i<13;++i){
    int h = hv[i], l = lv2[i], logh = 12-i;
    int total = (h>=4) ? 16*16*(h>>2) : 256;
    k_decompT<<<dim3((total+255)/256),256,0,stream>>>(ST[i-1], Dscr, ST[i], CSM, h, total);
    const float* cT = TWD + lt.twoff[i-6];
    k_fwdeep2<<<dim3(16,2),256,0,stream>>>(Dscr, ST[i], FTP, cT, h, l, logh);
    k_modemixT<<<dim3(l,16),128,0,stream>>>(FTP, WT, YT, h, 1);
    k_invdeep2<<<dim3(16,2),256,0,stream>>>(YT, Ud[i], Us[i], cT, h, l);
  }
  k_lngelu<<<dim3(16),128,0,stream>>>(ST[12], CSM, XA);
  bfu* rin = XA;
  for(int i=12;i>=0;--i){
    int h = hv[i];
    void* rout = (i==0) ? d_out : (void*)((rin==XA) ? XB : XA);
    int tot = 16*h*16;
    k_recon<<<dim3((tot+255)/256),256,0,stream>>>(rin, Us[i], Ud[i], CSM, rout, h, 12-i, (i==0)?1:0, FLAG);
    rin = (bfu*)rout;
  }
}